// Round 15
// baseline (113.907 us; speedup 1.0000x reference)
//
#include <hip/hip_runtime.h>

#define HF 240      // fine height/width
#define HC 60       // coarse height/width
#define STRIDEF 4   // HF/HC
#define PADW 2      // WINDOW//2
#define WIN 5
#define CC 256      // C_COARSE
#define CF 128      // C_FINE
#define NPOS 25     // WIN*WIN
#define NPX (HF*HF) // 57600 pixels per image
#define MPB 16      // matches per block in k_coarse (MPB=32 regressed 18x, R9)
#define TPX 64      // px per k_tgemm block tile
#define NSLAB (NPX / TPX)   // 900 slabs per slot
#define CAP 256     // entries per slab list (mean ~42; 256 = huge margin)

typedef __bf16 bf16x8 __attribute__((ext_vector_type(8)));
typedef __bf16 bf16x4 __attribute__((ext_vector_type(4)));
typedef float  f32x4  __attribute__((ext_vector_type(4)));
typedef float  f32x2  __attribute__((ext_vector_type(2)));

// ---------------------------------------------------------------------------
// K1: grid=128 (j), block=256 (k). Also zeroes the slab counters.
//   Wm1h[j][k<128] = bf16(W_merge[j][k])
//   W_effT[k][j]   = sum_q Wm2[j][q] * W_dp[q][k]
//   b_eff[j]       = Wm2[j]·b_dp + b_merge[j]
// ---------------------------------------------------------------------------
__global__ void k_prep(const float* __restrict__ W_dp, const float* __restrict__ b_dp,
                       const float* __restrict__ W_merge, const float* __restrict__ b_merge,
                       __bf16* __restrict__ Wm1h, float* __restrict__ W_effT,
                       float* __restrict__ b_eff, uint* __restrict__ cnt) {
    const int j = blockIdx.x;    // 0..127 output channel
    const int k = threadIdx.x;   // 0..255 coarse dim

    const int tid = j * 256 + k;
    if (tid < 4 * NSLAB) cnt[tid] = 0;     // zero slab counters every call

    const float* wm2 = W_merge + (size_t)j * (2 * CF) + CF;
    float acc = 0.f, accb = 0.f;
    for (int q = 0; q < CF; ++q) {
        const float wq = wm2[q];                    // wave-uniform
        acc  += wq * W_dp[(size_t)q * CC + k];      // coalesced
        accb += wq * b_dp[q];
    }
    W_effT[(size_t)k * CF + j] = acc;

    if (k < CF)
        Wm1h[(size_t)j * CF + k] = (__bf16)W_merge[(size_t)j * (2 * CF) + k];
    if (k == 0)
        b_eff[j] = accb + b_merge[j];
}

// ---------------------------------------------------------------------------
// K2: c_all[m][j] = b_eff[j] + sum_k W_eff[j][k] * coarse_vec(m)[k]
// ---------------------------------------------------------------------------
__global__ void k_coarse(const float* __restrict__ c1, const float* __restrict__ c2,
                         const int* __restrict__ bidx, const int* __restrict__ ridx,
                         const int* __restrict__ cidx, int M,
                         const float* __restrict__ W_effT, const float* __restrict__ b_eff,
                         float* __restrict__ c_all) {
    const int m0 = blockIdx.x * MPB;
    const int j  = threadIdx.x;  // 0..127
    const int twoM = 2 * M;
    __shared__ float v[MPB * CC];   // 16 KB

    const int nm = (twoM - m0) < MPB ? (twoM - m0) : MPB;
    for (int mm = 0; mm < nm; ++mm) {
        int m = m0 + mm;
        const float* src;
        if (m < M) src = c1 + ((size_t)bidx[m] * (HC * HC) + ridx[m]) * CC;
        else       src = c2 + ((size_t)bidx[m - M] * (HC * HC) + cidx[m - M]) * CC;
        v[mm * CC + j]      = src[j];
        v[mm * CC + j + CF] = src[j + CF];
    }
    __syncthreads();

    float acc[MPB];
    const float be = b_eff[j];
    #pragma unroll
    for (int mm = 0; mm < MPB; ++mm) acc[mm] = be;

    for (int k = 0; k < CC; k += 4) {
        float w0 = W_effT[(k + 0) * CF + j];
        float w1 = W_effT[(k + 1) * CF + j];
        float w2 = W_effT[(k + 2) * CF + j];
        float w3 = W_effT[(k + 3) * CF + j];
        #pragma unroll
        for (int mm = 0; mm < MPB; ++mm) {
            const f32x4 vv = *(const f32x4*)&v[mm * CC + k];
            acc[mm] += w0 * vv.x + w1 * vv.y + w2 * vv.z + w3 * vv.w;
        }
    }
    for (int mm = 0; mm < nm; ++mm)
        c_all[(size_t)(m0 + mm) * CF + j] = acc[mm];
}

// ---------------------------------------------------------------------------
// KI: inverse index. One thread per (m, p): append (m,p,pixel%64) to the
// slab list of the pixel it reads. Atomic order is irrelevant (each entry
// writes a distinct out row later). grid = ceil(2M*32/256).
// ---------------------------------------------------------------------------
__global__ __launch_bounds__(256) void k_index(
    const int* __restrict__ bidx, const int* __restrict__ ridx,
    const int* __restrict__ cidx, int M,
    uint* __restrict__ cnt, uint* __restrict__ entries) {
    const int tid = blockIdx.x * 256 + threadIdx.x;
    const int m = tid >> 5, pp = tid & 31;
    if (m >= 2 * M || pp >= NPOS) return;
    int b, lin;
    if (m < M) { b = bidx[m];     lin = ridx[m]; }
    else       { b = bidx[m - M]; lin = cidx[m - M]; }
    const int slot = (m < M ? 0 : 2) + b;
    const int r = lin / HC, c = lin - r * HC;
    const int wy = pp / WIN, wx = pp - wy * WIN;
    const int y = r * STRIDEF - PADW + wy;
    const int x = c * STRIDEF - PADW + wx;
    if (y < 0 || x < 0) return;            // zero-window rows: k_edge
    const int pixel = y * HF + x;
    const int cslab = slot * NSLAB + pixel / TPX;
    const uint idx = atomicAdd(&cnt[cslab], 1u);
    if (idx < CAP)
        entries[(size_t)cslab * CAP + idx] =
            ((uint)m << 11) | ((uint)pp << 6) | (uint)(pixel % TPX);
}

// ---------------------------------------------------------------------------
// KTG v9: R14 read pipeline + fused scatter epilogue (V never materialized).
// Block (256 thr, 4 waves) = 64 px x 128 ch; 4 K-chunks, dbuf LDS staging.
// After MFMA: stash V-slab (64px x 128j fp32) into LDS (reusing the staging
// buffer), then walk this slab's entry list: one wave writes one full 512B
// out row per entry: out[m][p][:] = vs[pxl][:] + c_all[m][:].
// grid = (900, 4), block = 256.
// ---------------------------------------------------------------------------
__global__ __launch_bounds__(256, 4) void k_tgemm(
    const float* __restrict__ f1, const float* __restrict__ f2,
    const __bf16* __restrict__ Wm1h, const float* __restrict__ c_all,
    const uint* __restrict__ cnt, const uint* __restrict__ entries,
    float* __restrict__ out) {

    int slab = blockIdx.x;           // 0..899
    {   // bijective XCD-chunked remap: q=112, r=4 (kept from R13/R14)
        const int q = NSLAB / 8, r = NSLAB % 8;
        const int xcd = slab & 7, off = slab >> 3;
        slab = (xcd < r ? xcd * (q + 1) : r * (q + 1) + (xcd - r) * q) + off;
    }
    const int slot = blockIdx.y;
    const float* src = (slot >= 2 ? f2 : f1) + (size_t)(slot & 1) * CF * NPX;
    const int px0 = slab * TPX;
    const int t  = threadIdx.x;
    const int l  = t & 63;
    const int w  = t >> 6;           // wave 0..3, owns j = w*32..+31
    const int lo16 = l & 15;
    const int hi   = l >> 4;

    // 32 KB: staging uses [0..4096); V-slab stash reuses all of it afterwards
    __shared__ __attribute__((aligned(16))) float smem[TPX * CF];

    const int q4 = lo16 * 4;         // px quad base within 64-px tile

#define STAGE(c, b)                                                           \
    {                                                                         \
        _Pragma("unroll")                                                     \
        for (int ii = 0; ii < 2; ++ii) {                                      \
            const int i  = w * 2 + ii;          /* instr 0..7 */              \
            const int ch = (c) * 32 + i * 4 + hi;                             \
            const int pxg = q4 ^ (((ch >> 3) & 3) << 4);                      \
            const float* gp = src + (size_t)ch * NPX + px0 + pxg;             \
            __builtin_amdgcn_global_load_lds(                                 \
                (const __attribute__((address_space(1))) void*)gp,            \
                (__attribute__((address_space(3))) void*)                     \
                    &smem[(b) * 2048 + i * 256],                              \
                16, 0, 0);                                                    \
        }                                                                     \
    }

    f32x4 acc[4][2];
    #pragma unroll
    for (int mt = 0; mt < 4; ++mt) {
        acc[mt][0] = (f32x4){0.f, 0.f, 0.f, 0.f};
        acc[mt][1] = (f32x4){0.f, 0.f, 0.f, 0.f};
    }

    STAGE(0, 0);

    #pragma unroll
    for (int c = 0; c < 4; ++c) {
        const int b = c & 1;
        if (c < 3) STAGE(c + 1, b ^ 1);
        __syncthreads();

        const bf16x8 bf0 = *reinterpret_cast<const bf16x8*>(
            Wm1h + (size_t)(w * 32 + 2 * lo16 + 0) * CF + c * 32 + hi * 8);
        const bf16x8 bf1 = *reinterpret_cast<const bf16x8*>(
            Wm1h + (size_t)(w * 32 + 2 * lo16 + 1) * CF + c * 32 + hi * 8);

        #pragma unroll
        for (int mt = 0; mt < 4; ++mt) {
            const int pxr = (mt * 16 + lo16) ^ (hi << 4);   // swizzled read col
            bf16x8 a;
            #pragma unroll
            for (int e = 0; e < 8; ++e)
                a[e] = (__bf16)smem[b * 2048 + (hi * 8 + e) * TPX + pxr];
            acc[mt][0] = __builtin_amdgcn_mfma_f32_16x16x32_bf16(a, bf0, acc[mt][0], 0, 0, 0);
            acc[mt][1] = __builtin_amdgcn_mfma_f32_16x16x32_bf16(a, bf1, acc[mt][1], 0, 0, 0);
        }
        __syncthreads();
    }
#undef STAGE

    // stash V-slab: vs[px][j] fp32 (overwrites staging buffer — post-barrier)
    #pragma unroll
    for (int mt = 0; mt < 4; ++mt) {
        #pragma unroll
        for (int reg = 0; reg < 4; ++reg) {
            const int px = mt * 16 + hi * 4 + reg;
            smem[px * CF + w * 32 + 2 * lo16 + 0] = acc[mt][0][reg];
            smem[px * CF + w * 32 + 2 * lo16 + 1] = acc[mt][1][reg];
        }
    }
    __syncthreads();

    // scatter: one wave per entry, full 512B fp32 out row
    const int cslab = slot * NSLAB + slab;
    int count = (int)cnt[cslab];
    if (count > CAP) count = CAP;
    const uint* ep = entries + (size_t)cslab * CAP;
    for (int i = w; i < count; i += 4) {
        const uint e = ep[i];                 // wave-uniform -> scalar load
        const int pxl = e & 63;
        const int p   = (e >> 6) & 31;
        const int m   = e >> 11;
        const f32x2 v  = *(const f32x2*)&smem[pxl * CF + 2 * l];
        const f32x2 cv = *(const f32x2*)(c_all + (size_t)m * CF + 2 * l);
        f32x2 o = { v.x + cv.x, v.y + cv.y };
        *(f32x2*)(out + ((size_t)m * NPOS + p) * CF + 2 * l) = o;
    }
}

// ---------------------------------------------------------------------------
// KE: clipped (zero-window) rows: out[m][p][:] = c_all[m][:].
// grid = 2M, block = 256 (wave g handles p = g, g+4, ...).
// ---------------------------------------------------------------------------
__global__ __launch_bounds__(256) void k_edge(
    const int* __restrict__ bidx, const int* __restrict__ ridx,
    const int* __restrict__ cidx, int M,
    const float* __restrict__ c_all, float* __restrict__ out) {
    const int m = blockIdx.x;
    const int t = threadIdx.x;
    const int wv = t >> 6, l = t & 63;
    int b, lin;
    if (m < M) { b = bidx[m];     lin = ridx[m]; }
    else       { b = bidx[m - M]; lin = cidx[m - M]; }
    (void)b;
    const int r = lin / HC, c = lin - r * HC;
    const int y0 = r * STRIDEF - PADW;
    const int x0 = c * STRIDEF - PADW;
    if (y0 >= 0 && x0 >= 0) return;       // no clipped positions
    const f32x2 cv = *(const f32x2*)(c_all + (size_t)m * CF + 2 * l);
    for (int p = wv; p < NPOS; p += 4) {
        const int wy = (p * 13) >> 6;     // p/5 for p<32
        const int wx = p - wy * WIN;
        if (y0 + wy < 0 || x0 + wx < 0)
            *(f32x2*)(out + ((size_t)m * NPOS + p) * CF + 2 * l) = cv;
    }
}

// ---------------------------------------------------------------------------
// Fallback main (R2 path): gather directly from fp32 NCHW images.
// ---------------------------------------------------------------------------
__global__ __launch_bounds__(256) void k_main_direct(
    const float* __restrict__ f1, const float* __restrict__ f2,
    const int* __restrict__ bidx, const int* __restrict__ ridx,
    const int* __restrict__ cidx, int M,
    const __bf16* __restrict__ Wm1h, const float* __restrict__ c_all,
    float* __restrict__ out) {

    const int m = blockIdx.x;
    const int t = threadIdx.x;
    const int l    = t & 63;
    const int wv   = t >> 6;
    const int lo16 = l & 15;
    const int hi   = l >> 4;

    __shared__ __bf16 patch[32 * CF];

    bf16x8 bfrag[2][4];
    #pragma unroll
    for (int nt2 = 0; nt2 < 2; ++nt2) {
        const int j = wv * 32 + nt2 * 16 + lo16;
        #pragma unroll
        for (int kt = 0; kt < 4; ++kt)
            bfrag[nt2][kt] = *reinterpret_cast<const bf16x8*>(Wm1h + (size_t)j * CF + kt * 32 + hi * 8);
    }

    const float* img; int b, lin;
    if (m < M) { img = f1; b = bidx[m];     lin = ridx[m]; }
    else       { img = f2; b = bidx[m - M]; lin = cidx[m - M]; }
    const int r  = lin / HC, c = lin - r * HC;
    const int y0 = r * STRIDEF - PADW;
    const int x0 = c * STRIDEF - PADW;

    for (int task = t; task < CF * WIN; task += 256) {
        const int ch = task / WIN;
        const int wy = task - ch * WIN;
        const int y  = y0 + wy;
        const bool yok = (y >= 0);
        const float* rowp = img + (((size_t)b * CF + ch) * HF + (yok ? y : 0)) * HF;
        #pragma unroll
        for (int wx = 0; wx < WIN; ++wx) {
            const int x = x0 + wx;
            const float val = (yok && x >= 0) ? rowp[x] : 0.f;
            const int pos = wy * WIN + wx;
            patch[pos * CF + (ch ^ ((pos & 7) << 3))] = (__bf16)val;
        }
    }
    __syncthreads();

    f32x4 acc[2][2];
    #pragma unroll
    for (int mt = 0; mt < 2; ++mt)
        #pragma unroll
        for (int nt2 = 0; nt2 < 2; ++nt2)
            acc[mt][nt2] = (f32x4){0.f, 0.f, 0.f, 0.f};

    const int swz = (lo16 & 7) << 3;
    #pragma unroll
    for (int kt = 0; kt < 4; ++kt) {
        const int koff = (kt * 32 + hi * 8) ^ swz;
        bf16x8 a0 = *reinterpret_cast<const bf16x8*>(&patch[ lo16       * CF + koff]);
        bf16x8 a1 = *reinterpret_cast<const bf16x8*>(&patch[(16 + lo16) * CF + koff]);
        #pragma unroll
        for (int nt2 = 0; nt2 < 2; ++nt2) {
            acc[0][nt2] = __builtin_amdgcn_mfma_f32_16x16x32_bf16(a0, bfrag[nt2][kt], acc[0][nt2], 0, 0, 0);
            acc[1][nt2] = __builtin_amdgcn_mfma_f32_16x16x32_bf16(a1, bfrag[nt2][kt], acc[1][nt2], 0, 0, 0);
        }
    }

    float* ob = out + (size_t)m * (NPOS * CF);
    #pragma unroll
    for (int nt2 = 0; nt2 < 2; ++nt2) {
        const int j  = wv * 32 + nt2 * 16 + lo16;
        const float cv = c_all[(size_t)m * CF + j];
        #pragma unroll
        for (int mt = 0; mt < 2; ++mt) {
            #pragma unroll
            for (int reg = 0; reg < 4; ++reg) {
                const int p = mt * 16 + hi * 4 + reg;
                if (p < NPOS)
                    ob[(size_t)p * CF + j] = acc[mt][nt2][reg] + cv;
            }
        }
    }
}

// ---------------------------------------------------------------------------
extern "C" void kernel_launch(void* const* d_in, const int* in_sizes, int n_in,
                              void* d_out, int out_size, void* d_ws, size_t ws_size,
                              hipStream_t stream) {
    const float* c1      = (const float*)d_in[0];
    const float* c2      = (const float*)d_in[1];
    const float* f1      = (const float*)d_in[2];
    const float* f2      = (const float*)d_in[3];
    const int*   bidx    = (const int*)d_in[4];
    const int*   ridx    = (const int*)d_in[5];
    const int*   cidx    = (const int*)d_in[6];
    const float* W_dp    = (const float*)d_in[9];
    const float* b_dp    = (const float*)d_in[10];
    const float* W_merge = (const float*)d_in[11];
    const float* b_merge = (const float*)d_in[12];
    const int M = in_sizes[4];

    char* ws = (char*)d_ws;
    __bf16* Wm1h   = (__bf16*)(ws);                //  32 KB
    float*  W_effT = (float*)(ws + (64 << 10));    // 128 KB
    float*  b_eff  = (float*)(ws + (192 << 10));   // 512 B
    float*  c_all  = (float*)(ws + (256 << 10));   // 2M*128*4 ~ 3.07 MB
    uint*   cnt    = (uint*)(ws + (4 << 20));      // 3600 * 4 B
    uint*   entr   = (uint*)(ws + (5 << 20));      // 3600*256*4 = 3.69 MB

    const size_t need = (size_t)(5 << 20) + (size_t)4 * NSLAB * CAP * 4;

    hipLaunchKernelGGL(k_prep, dim3(CF), dim3(CC), 0, stream,
                       W_dp, b_dp, W_merge, b_merge, Wm1h, W_effT, b_eff, cnt);
    hipLaunchKernelGGL(k_coarse, dim3((2 * M + MPB - 1) / MPB), dim3(CF), 0, stream,
                       c1, c2, bidx, ridx, cidx, M, W_effT, b_eff, c_all);

    if (ws_size >= need) {
        const int nidx = (2 * M * 32 + 255) / 256;
        hipLaunchKernelGGL(k_index, dim3(nidx), dim3(256), 0, stream,
                           bidx, ridx, cidx, M, cnt, entr);
        hipLaunchKernelGGL(k_tgemm, dim3(NSLAB, 4), dim3(256), 0, stream,
                           f1, f2, Wm1h, c_all, cnt, entr, (float*)d_out);
        hipLaunchKernelGGL(k_edge, dim3(2 * M), dim3(256), 0, stream,
                           bidx, ridx, cidx, M, c_all, (float*)d_out);
    } else {
        hipLaunchKernelGGL(k_main_direct, dim3(2 * M), dim3(256), 0, stream,
                           f1, f2, bidx, ridx, cidx, M, Wm1h, c_all, (float*)d_out);
    }
}

// Round 16
// 92.779 us; speedup vs baseline: 1.2277x; 1.2277x over previous
//
#include <hip/hip_runtime.h>

#define HF 240      // fine height/width
#define HC 60       // coarse height/width
#define STRIDEF 4   // HF/HC
#define PADW 2      // WINDOW//2
#define WIN 5
#define CC 256      // C_COARSE
#define CF 128      // C_FINE
#define NPOS 25     // WIN*WIN
#define NPX (HF*HF) // 57600 pixels per image
#define MPB 16      // matches per block in k_coarse (MPB=32 regressed 18x, R9)
#define TPX 128     // px per k_tgemm block tile

typedef __bf16 bf16x8 __attribute__((ext_vector_type(8)));
typedef __bf16 bf16x4 __attribute__((ext_vector_type(4)));
typedef float  f32x4  __attribute__((ext_vector_type(4)));

// ---------------------------------------------------------------------------
// K1: grid=128 (j), block=256 (k).
//   Wm1h[j][k<128] = bf16(W_merge[j][k])
//   W_effT[k][j]   = sum_q Wm2[j][q] * W_dp[q][k]
//   b_eff[j]       = Wm2[j]·b_dp + b_merge[j]
// ---------------------------------------------------------------------------
__global__ void k_prep(const float* __restrict__ W_dp, const float* __restrict__ b_dp,
                       const float* __restrict__ W_merge, const float* __restrict__ b_merge,
                       __bf16* __restrict__ Wm1h, float* __restrict__ W_effT,
                       float* __restrict__ b_eff) {
    const int j = blockIdx.x;    // 0..127 output channel
    const int k = threadIdx.x;   // 0..255 coarse dim
    const float* wm2 = W_merge + (size_t)j * (2 * CF) + CF;

    float acc = 0.f, accb = 0.f;
    for (int q = 0; q < CF; ++q) {
        const float wq = wm2[q];                    // wave-uniform
        acc  += wq * W_dp[(size_t)q * CC + k];      // coalesced
        accb += wq * b_dp[q];
    }
    W_effT[(size_t)k * CF + j] = acc;

    if (k < CF)
        Wm1h[(size_t)j * CF + k] = (__bf16)W_merge[(size_t)j * (2 * CF) + k];
    if (k == 0)
        b_eff[j] = accb + b_merge[j];
}

// ---------------------------------------------------------------------------
// K2: c_all[m][j] = b_eff[j] + sum_k W_eff[j][k] * coarse_vec(m)[k]
// 16 matches/block -> 375 blocks (>1/CU).
// ---------------------------------------------------------------------------
__global__ void k_coarse(const float* __restrict__ c1, const float* __restrict__ c2,
                         const int* __restrict__ bidx, const int* __restrict__ ridx,
                         const int* __restrict__ cidx, int M,
                         const float* __restrict__ W_effT, const float* __restrict__ b_eff,
                         float* __restrict__ c_all) {
    const int m0 = blockIdx.x * MPB;
    const int j  = threadIdx.x;  // 0..127
    const int twoM = 2 * M;
    __shared__ float v[MPB * CC];   // 16 KB

    const int nm = (twoM - m0) < MPB ? (twoM - m0) : MPB;
    for (int mm = 0; mm < nm; ++mm) {
        int m = m0 + mm;
        const float* src;
        if (m < M) src = c1 + ((size_t)bidx[m] * (HC * HC) + ridx[m]) * CC;
        else       src = c2 + ((size_t)bidx[m - M] * (HC * HC) + cidx[m - M]) * CC;
        v[mm * CC + j]      = src[j];
        v[mm * CC + j + CF] = src[j + CF];
    }
    __syncthreads();

    float acc[MPB];
    const float be = b_eff[j];
    #pragma unroll
    for (int mm = 0; mm < MPB; ++mm) acc[mm] = be;

    for (int k = 0; k < CC; k += 4) {
        float w0 = W_effT[(k + 0) * CF + j];
        float w1 = W_effT[(k + 1) * CF + j];
        float w2 = W_effT[(k + 2) * CF + j];
        float w3 = W_effT[(k + 3) * CF + j];
        #pragma unroll
        for (int mm = 0; mm < MPB; ++mm) {
            const f32x4 vv = *(const f32x4*)&v[mm * CC + k];
            acc[mm] += w0 * vv.x + w1 * vv.y + w2 * vv.z + w3 * vv.w;
        }
    }
    for (int mm = 0; mm < nm; ++mm)
        c_all[(size_t)(m0 + mm) * CF + j] = acc[mm];
}

// ---------------------------------------------------------------------------
// KTG v5 (best-measured, R8/R10): m97-structure transpose+GEMM, gload_lds.
// Block (256 thr, 4 waves) = 128 px x 128 ch; 4 K-chunks of 32 ch,
// double-buffered fp32 LDS [32ch][128px] (2 x 16 KB).
// Strided fetch pinned at ~1 TB/s by pattern (4 clean nulls: run length,
// ordering, occupancy, conflicts — R8/R13/R14). grid = (450, 4), block = 256.
// ---------------------------------------------------------------------------
__global__ __launch_bounds__(256, 4) void k_tgemm(
    const float* __restrict__ f1, const float* __restrict__ f2,
    const __bf16* __restrict__ Wm1h, __bf16* __restrict__ V) {

    const int slot = blockIdx.y;
    const float* src = (slot >= 2 ? f2 : f1) + (size_t)(slot & 1) * CF * NPX;
    const int px0 = blockIdx.x * TPX;
    const int t  = threadIdx.x;
    const int l  = t & 63;
    const int w  = t >> 6;           // wave 0..3, owns j = w*32..+31
    const int lo16 = l & 15;
    const int hi   = l >> 4;

    __shared__ __attribute__((aligned(16))) float chkf[2][32 * TPX]; // 2 x 16 KB

    const int seg = l >> 5;          // 0/1: which ch row within an instr
    const int q4  = (l & 31) * 4;    // LDS px' quad base

#define STAGE(c, b)                                                           \
    {                                                                         \
        _Pragma("unroll")                                                     \
        for (int ii = 0; ii < 4; ++ii) {                                      \
            const int i   = w * 4 + ii;                                       \
            const int chl = 2 * i + seg;                                      \
            const int ch  = (c) * 32 + chl;                                   \
            const int pxg = q4 ^ (((ch >> 3) & 3) << 4);                      \
            const float* gp = src + (size_t)ch * NPX + px0 + pxg;             \
            __builtin_amdgcn_global_load_lds(                                 \
                (const __attribute__((address_space(1))) void*)gp,            \
                (__attribute__((address_space(3))) void*)&chkf[b][i * 256],   \
                16, 0, 0);                                                    \
        }                                                                     \
    }

    f32x4 acc[8][2];
    #pragma unroll
    for (int mt = 0; mt < 8; ++mt) {
        acc[mt][0] = (f32x4){0.f, 0.f, 0.f, 0.f};
        acc[mt][1] = (f32x4){0.f, 0.f, 0.f, 0.f};
    }

    STAGE(0, 0);

    #pragma unroll
    for (int c = 0; c < 4; ++c) {
        const int b = c & 1;
        if (c < 3) STAGE(c + 1, b ^ 1);
        __syncthreads();

        const bf16x8 bf0 = *reinterpret_cast<const bf16x8*>(
            Wm1h + (size_t)(w * 32 + 2 * lo16 + 0) * CF + c * 32 + hi * 8);
        const bf16x8 bf1 = *reinterpret_cast<const bf16x8*>(
            Wm1h + (size_t)(w * 32 + 2 * lo16 + 1) * CF + c * 32 + hi * 8);

        #pragma unroll
        for (int mt = 0; mt < 8; ++mt) {
            const int pxr = (mt * 16 + lo16) ^ (hi << 4);   // swizzled read col
            bf16x8 a;
            #pragma unroll
            for (int e = 0; e < 8; ++e)
                a[e] = (__bf16)chkf[b][(hi * 8 + e) * TPX + pxr];
            acc[mt][0] = __builtin_amdgcn_mfma_f32_16x16x32_bf16(a, bf0, acc[mt][0], 0, 0, 0);
            acc[mt][1] = __builtin_amdgcn_mfma_f32_16x16x32_bf16(a, bf1, acc[mt][1], 0, 0, 0);
        }
        __syncthreads();
    }
#undef STAGE

    // epilogue: V[px][j], dword = (j_even, j_odd) bf16x2
    uint* Vp = (uint*)(V + ((size_t)slot * NPX + px0) * CF);
    const int dcol = w * 16 + lo16;
    #pragma unroll
    for (int mt = 0; mt < 8; ++mt) {
        #pragma unroll
        for (int reg = 0; reg < 4; ++reg) {
            const int px = mt * 16 + hi * 4 + reg;
            union { uint u; __bf16 h[2]; } cv;
            cv.h[0] = (__bf16)acc[mt][0][reg];
            cv.h[1] = (__bf16)acc[mt][1][reg];
            Vp[(size_t)px * 64 + dcol] = cv.u;
        }
    }
}

// ---------------------------------------------------------------------------
// K4: gather-add stream with NON-TEMPORAL out stores.
// grid = 2M, block = 256. No LDS, no sync.
// ---------------------------------------------------------------------------
__global__ __launch_bounds__(256) void k_gather(
    const __bf16* __restrict__ V,
    const int* __restrict__ bidx, const int* __restrict__ ridx,
    const int* __restrict__ cidx, int M,
    const float* __restrict__ c_all, float* __restrict__ out) {

    const int m = blockIdx.x;
    const int t = threadIdx.x;
    const int g  = t >> 5;    // row group 0..7
    const int l32 = t & 31;   // covers 128 ch as 32 float4

    int b, lin, ii;
    if (m < M) { ii = 0; b = bidx[m];     lin = ridx[m]; }
    else       { ii = 1; b = bidx[m - M]; lin = cidx[m - M]; }
    const int slot = ii * 2 + b;
    const int r  = lin / HC, c = lin - r * HC;
    const int y0 = r * STRIDEF - PADW;
    const int x0 = c * STRIDEF - PADW;

    const f32x4 c4 = *reinterpret_cast<const f32x4*>(c_all + (size_t)m * CF + l32 * 4);
    const __bf16* Vb = V + (size_t)slot * NPX * CF;
    float* ob = out + (size_t)m * (NPOS * CF) + l32 * 4;

    #pragma unroll
    for (int pass = 0; pass < 4; ++pass) {
        const int p = pass * 8 + g;
        if (p < NPOS) {
            const int wy = (p * 13) >> 6;      // p/5 for p<32
            const int wx = p - wy * WIN;
            const int y = y0 + wy, x = x0 + wx;
            f32x4 o = c4;
            if (y >= 0 && x >= 0) {
                const bf16x4 v = *reinterpret_cast<const bf16x4*>(Vb + (size_t)(y * HF + x) * CF + l32 * 4);
                o.x += (float)v.x; o.y += (float)v.y; o.z += (float)v.z; o.w += (float)v.w;
            }
            __builtin_nontemporal_store(o, reinterpret_cast<f32x4*>(ob + (size_t)p * CF));
        }
    }
}

// ---------------------------------------------------------------------------
// Fallback main (R2 path): gather directly from fp32 NCHW images.
// ---------------------------------------------------------------------------
__global__ __launch_bounds__(256) void k_main_direct(
    const float* __restrict__ f1, const float* __restrict__ f2,
    const int* __restrict__ bidx, const int* __restrict__ ridx,
    const int* __restrict__ cidx, int M,
    const __bf16* __restrict__ Wm1h, const float* __restrict__ c_all,
    float* __restrict__ out) {

    const int m = blockIdx.x;
    const int t = threadIdx.x;
    const int l    = t & 63;
    const int wv   = t >> 6;
    const int lo16 = l & 15;
    const int hi   = l >> 4;

    __shared__ __bf16 patch[32 * CF];

    bf16x8 bfrag[2][4];
    #pragma unroll
    for (int nt2 = 0; nt2 < 2; ++nt2) {
        const int j = wv * 32 + nt2 * 16 + lo16;
        #pragma unroll
        for (int kt = 0; kt < 4; ++kt)
            bfrag[nt2][kt] = *reinterpret_cast<const bf16x8*>(Wm1h + (size_t)j * CF + kt * 32 + hi * 8);
    }

    const float* img; int b, lin;
    if (m < M) { img = f1; b = bidx[m];     lin = ridx[m]; }
    else       { img = f2; b = bidx[m - M]; lin = cidx[m - M]; }
    const int r  = lin / HC, c = lin - r * HC;
    const int y0 = r * STRIDEF - PADW;
    const int x0 = c * STRIDEF - PADW;

    for (int task = t; task < CF * WIN; task += 256) {
        const int ch = task / WIN;
        const int wy = task - ch * WIN;
        const int y  = y0 + wy;
        const bool yok = (y >= 0);
        const float* rowp = img + (((size_t)b * CF + ch) * HF + (yok ? y : 0)) * HF;
        #pragma unroll
        for (int wx = 0; wx < WIN; ++wx) {
            const int x = x0 + wx;
            const float val = (yok && x >= 0) ? rowp[x] : 0.f;
            const int pos = wy * WIN + wx;
            patch[pos * CF + (ch ^ ((pos & 7) << 3))] = (__bf16)val;
        }
    }
    __syncthreads();

    f32x4 acc[2][2];
    #pragma unroll
    for (int mt = 0; mt < 2; ++mt)
        #pragma unroll
        for (int nt2 = 0; nt2 < 2; ++nt2)
            acc[mt][nt2] = (f32x4){0.f, 0.f, 0.f, 0.f};

    const int swz = (lo16 & 7) << 3;
    #pragma unroll
    for (int kt = 0; kt < 4; ++kt) {
        const int koff = (kt * 32 + hi * 8) ^ swz;
        bf16x8 a0 = *reinterpret_cast<const bf16x8*>(&patch[ lo16       * CF + koff]);
        bf16x8 a1 = *reinterpret_cast<const bf16x8*>(&patch[(16 + lo16) * CF + koff]);
        #pragma unroll
        for (int nt2 = 0; nt2 < 2; ++nt2) {
            acc[0][nt2] = __builtin_amdgcn_mfma_f32_16x16x32_bf16(a0, bfrag[nt2][kt], acc[0][nt2], 0, 0, 0);
            acc[1][nt2] = __builtin_amdgcn_mfma_f32_16x16x32_bf16(a1, bfrag[nt2][kt], acc[1][nt2], 0, 0, 0);
        }
    }

    float* ob = out + (size_t)m * (NPOS * CF);
    #pragma unroll
    for (int nt2 = 0; nt2 < 2; ++nt2) {
        const int j  = wv * 32 + nt2 * 16 + lo16;
        const float cv = c_all[(size_t)m * CF + j];
        #pragma unroll
        for (int mt = 0; mt < 2; ++mt) {
            #pragma unroll
            for (int reg = 0; reg < 4; ++reg) {
                const int p = mt * 16 + hi * 4 + reg;
                if (p < NPOS)
                    ob[(size_t)p * CF + j] = acc[mt][nt2][reg] + cv;
            }
        }
    }
}

// ---------------------------------------------------------------------------
extern "C" void kernel_launch(void* const* d_in, const int* in_sizes, int n_in,
                              void* d_out, int out_size, void* d_ws, size_t ws_size,
                              hipStream_t stream) {
    const float* c1      = (const float*)d_in[0];
    const float* c2      = (const float*)d_in[1];
    const float* f1      = (const float*)d_in[2];
    const float* f2      = (const float*)d_in[3];
    const int*   bidx    = (const int*)d_in[4];
    const int*   ridx    = (const int*)d_in[5];
    const int*   cidx    = (const int*)d_in[6];
    const float* W_dp    = (const float*)d_in[9];
    const float* b_dp    = (const float*)d_in[10];
    const float* W_merge = (const float*)d_in[11];
    const float* b_merge = (const float*)d_in[12];
    const int M = in_sizes[4];

    char* ws = (char*)d_ws;
    __bf16* Wm1h  = (__bf16*)(ws);                //  32 KB
    float* W_effT = (float*)(ws + (64 << 10));    // 128 KB
    float* b_eff  = (float*)(ws + (192 << 10));   // 512 B
    float* c_all  = (float*)(ws + (256 << 10));   // 2M*128*4 ~ 3.07 MB
    __bf16* V     = (__bf16*)(ws + (4 << 20));    // 4*57600*128*2 = 58.98 MB

    const size_t need_V = (size_t)(4 << 20) + (size_t)4 * NPX * CF * 2;

    hipLaunchKernelGGL(k_prep, dim3(CF), dim3(CC), 0, stream,
                       W_dp, b_dp, W_merge, b_merge, Wm1h, W_effT, b_eff);
    hipLaunchKernelGGL(k_coarse, dim3((2 * M + MPB - 1) / MPB), dim3(CF), 0, stream,
                       c1, c2, bidx, ridx, cidx, M, W_effT, b_eff, c_all);

    if (ws_size >= need_V) {
        hipLaunchKernelGGL(k_tgemm, dim3(NPX / TPX, 4), dim3(256), 0, stream,
                           f1, f2, Wm1h, V);
        hipLaunchKernelGGL(k_gather, dim3(2 * M), dim3(256), 0, stream,
                           V, bidx, ridx, cidx, M, c_all, (float*)d_out);
    } else {
        hipLaunchKernelGGL(k_main_direct, dim3(2 * M), dim3(256), 0, stream,
                           f1, f2, bidx, ridx, cidx, M, Wm1h, c_all, (float*)d_out);
    }
}